// Round 1
// baseline (652.377 us; speedup 1.0000x reference)
//
#include <hip/hip_runtime.h>
#include <math.h>

// Problem constants (from reference): x (32,3,224,224) f32, thetas (32,17) f32
// out (32,17,3,224,224) f32.
namespace {
constexpr int N_  = 32;
constexpr int S1_ = 17;   // S+1 thetas per batch
constexpr int C_  = 3;
constexpr int H_  = 224;
constexpr int W_  = 224;
constexpr int HW_ = H_ * W_;
constexpr int PIX_PER_THREAD = 4;    // one float4 store per channel
constexpr int THREADS = 256;
constexpr int BLOCKS_PER_PLANE = HW_ / (PIX_PER_THREAD * THREADS);  // 49
}

__global__ __launch_bounds__(THREADS) void rot_bilinear_kernel(
    const float* __restrict__ x,       // (N, C, H, W)
    const float* __restrict__ thetas,  // (N, S1)
    float* __restrict__ out) {         // (N, S1, C, H, W)
  const int ns = blockIdx.y;           // n * S1 + s
  const int n  = ns / S1_;

  const float theta = thetas[ns];
  float st, ct;
  sincosf(theta, &st, &ct);

  // 4 consecutive pixels along w (W=224 divisible by 4, so same row h).
  const int p  = (blockIdx.x * THREADS + threadIdx.x) * PIX_PER_THREAD;
  const int h  = p / W_;
  const int w0 = p - h * W_;

  const float ys = (h + 0.5f) * (2.0f / H_) - 1.0f;

  const float* __restrict__ img = x + (size_t)n * (C_ * HW_);

  int   idx00[PIX_PER_THREAD], idx01[PIX_PER_THREAD];
  int   idx10[PIX_PER_THREAD], idx11[PIX_PER_THREAD];
  float w00[PIX_PER_THREAD], w01[PIX_PER_THREAD];
  float w10[PIX_PER_THREAD], w11[PIX_PER_THREAD];

#pragma unroll
  for (int k = 0; k < PIX_PER_THREAD; ++k) {
    const float xs = (w0 + k + 0.5f) * (2.0f / W_) - 1.0f;
    // Rotation grid (matches reference expression order).
    const float gx = ct * xs - st * ys;
    const float gy = st * xs + ct * ys;
    const float fx = ((gx + 1.0f) * W_ - 1.0f) * 0.5f;
    const float fy = ((gy + 1.0f) * H_ - 1.0f) * 0.5f;
    const float fx0 = floorf(fx);
    const float fy0 = floorf(fy);
    const float wx1 = fx - fx0;
    const float wy1 = fy - fy0;
    const float wx0 = 1.0f - wx1;
    const float wy0 = 1.0f - wy1;
    const int ix0 = (int)fx0;
    const int iy0 = (int)fy0;
    const int ix1 = ix0 + 1;
    const int iy1 = iy0 + 1;
    // Zero-padding: validity folded into the weights; loads use clamped
    // (always in-bounds) addresses so there is no divergent branch.
    const float vx0 = (ix0 >= 0 && ix0 < W_) ? 1.0f : 0.0f;
    const float vx1 = (ix1 >= 0 && ix1 < W_) ? 1.0f : 0.0f;
    const float vy0 = (iy0 >= 0 && iy0 < H_) ? 1.0f : 0.0f;
    const float vy1 = (iy1 >= 0 && iy1 < H_) ? 1.0f : 0.0f;
    const int cx0 = min(max(ix0, 0), W_ - 1);
    const int cx1 = min(max(ix1, 0), W_ - 1);
    const int cy0 = min(max(iy0, 0), H_ - 1);
    const int cy1 = min(max(iy1, 0), H_ - 1);
    idx00[k] = cy0 * W_ + cx0;
    idx01[k] = cy0 * W_ + cx1;
    idx10[k] = cy1 * W_ + cx0;
    idx11[k] = cy1 * W_ + cx1;
    w00[k] = wy0 * wx0 * vy0 * vx0;
    w01[k] = wy0 * wx1 * vy0 * vx1;
    w10[k] = wy1 * wx0 * vy1 * vx0;
    w11[k] = wy1 * wx1 * vy1 * vx1;
  }

#pragma unroll
  for (int c = 0; c < C_; ++c) {
    const float* __restrict__ pl = img + (size_t)c * HW_;
    float r[PIX_PER_THREAD];
#pragma unroll
    for (int k = 0; k < PIX_PER_THREAD; ++k) {
      r[k] = w00[k] * pl[idx00[k]] + w01[k] * pl[idx01[k]] +
             w10[k] * pl[idx10[k]] + w11[k] * pl[idx11[k]];
    }
    float4 o = make_float4(r[0], r[1], r[2], r[3]);
    *reinterpret_cast<float4*>(
        out + ((size_t)(ns * C_ + c) * HW_) + (size_t)h * W_ + w0) = o;
  }
}

extern "C" void kernel_launch(void* const* d_in, const int* in_sizes, int n_in,
                              void* d_out, int out_size, void* d_ws,
                              size_t ws_size, hipStream_t stream) {
  const float* x      = (const float*)d_in[0];
  const float* thetas = (const float*)d_in[1];
  float* out          = (float*)d_out;

  dim3 grid(BLOCKS_PER_PLANE, N_ * S1_);
  rot_bilinear_kernel<<<grid, THREADS, 0, stream>>>(x, thetas, out);
}

// Round 2
// 407.868 us; speedup vs baseline: 1.5995x; 1.5995x over previous
//
#include <hip/hip_runtime.h>
#include <math.h>

// x (32,3,224,224) f32, thetas (32,17) f32 -> out (32,17,3,224,224) f32.
// Strategy: per-block 32x32 output tile of one (n,s) plane. Stage the rotated
// tile's 46x46 input window (all 3 channels) into LDS with zero-fill outside
// the image (implements zero-padding), then bilinear-gather from LDS.
namespace {
constexpr int N_  = 32;
constexpr int S1_ = 17;
constexpr int C_  = 3;
constexpr int H_  = 224;
constexpr int W_  = 224;
constexpr int HW_ = H_ * W_;
constexpr int TILE = 32;                 // output tile (TILE x TILE)
constexpr int TPL  = W_ / TILE;          // 7 tiles per row
constexpr int LW   = 46;                 // LDS window dim (>= 31*1.366+2+0.2 slack)
constexpr int LSTR = 47;                 // padded stride (bank-conflict break)
constexpr int THREADS = 256;
}

__global__ __launch_bounds__(THREADS) void rot_bilinear_lds_kernel(
    const float* __restrict__ x,       // (N, C, H, W)
    const float* __restrict__ thetas,  // (N, S1)
    float* __restrict__ out) {         // (N, S1, C, H, W)
  __shared__ float lds[C_][LW * LSTR];

  const int ns = blockIdx.y;           // n * S1 + s
  const int n  = ns / S1_;
  const int bx = blockIdx.x;           // tile id in plane
  const int h0 = (bx / TPL) * TILE;
  const int w0 = (bx % TPL) * TILE;

  const float theta = thetas[ns];
  float st, ct;
  sincosf(theta, &st, &ct);

  // ---- Window anchor: bbox of fx/fy over the tile (linear -> corners). ----
  // Same expression order as the per-pixel path / reference.
  float fxmin = 1e30f, fxmax = -1e30f, fymin = 1e30f, fymax = -1e30f;
#pragma unroll
  for (int cw = 0; cw < 2; ++cw) {
#pragma unroll
    for (int chh = 0; chh < 2; ++chh) {
      const float xs = ((w0 + cw * (TILE - 1)) + 0.5f) * (2.0f / W_) - 1.0f;
      const float ys = ((h0 + chh * (TILE - 1)) + 0.5f) * (2.0f / H_) - 1.0f;
      const float gx = ct * xs - st * ys;
      const float gy = st * xs + ct * ys;
      const float fx = ((gx + 1.0f) * W_ - 1.0f) * 0.5f;
      const float fy = ((gy + 1.0f) * H_ - 1.0f) * 0.5f;
      fxmin = fminf(fxmin, fx); fxmax = fmaxf(fxmax, fx);
      fymin = fminf(fymin, fy); fymax = fmaxf(fymax, fy);
    }
  }
  const int rx0 = (int)floorf(fxmin - 0.1f);   // window origin (image coords)
  const int ry0 = (int)floorf(fymin - 0.1f);

  // ---- Stage 46x46 window, 3 channels, zero-filled outside image. ----
  const float* __restrict__ img = x + (size_t)n * (C_ * HW_);
  const int tid = threadIdx.x;
  for (int i = tid; i < LW * LW; i += THREADS) {
    const int r = i / LW;
    const int c = i - r * LW;
    const int gy = ry0 + r;
    const int gx = rx0 + c;
    const bool in = (gx >= 0) & (gx < W_) & (gy >= 0) & (gy < H_);
    const int off = (in ? gy : 0) * W_ + (in ? gx : 0);
    const float m = in ? 1.0f : 0.0f;
    lds[0][r * LSTR + c] = img[off] * m;
    lds[1][r * LSTR + c] = img[HW_ + off] * m;
    lds[2][r * LSTR + c] = img[2 * HW_ + off] * m;
  }
  __syncthreads();

  // ---- Compute: each thread does 4 consecutive pixels of one tile row. ----
  const int row = tid >> 3;            // 0..31
  const int col = (tid & 7) * 4;       // 0,4,...,28
  const int h = h0 + row;
  const int w_base = w0 + col;
  const float ys = (h + 0.5f) * (2.0f / H_) - 1.0f;

  float r0[4], r1[4], r2[4];
#pragma unroll
  for (int k = 0; k < 4; ++k) {
    const float xs = (w_base + k + 0.5f) * (2.0f / W_) - 1.0f;
    const float gx = ct * xs - st * ys;
    const float gy = st * xs + ct * ys;
    const float fx = ((gx + 1.0f) * W_ - 1.0f) * 0.5f;
    const float fy = ((gy + 1.0f) * H_ - 1.0f) * 0.5f;
    const float fx0 = floorf(fx);
    const float fy0 = floorf(fy);
    const float wx1 = fx - fx0;
    const float wy1 = fy - fy0;
    const float wx0 = 1.0f - wx1;
    const float wy0 = 1.0f - wy1;
    // Window coords: always in-bounds by bbox construction (out-of-image
    // taps read staged zeros -> zero padding handled automatically).
    const int lx = (int)fx0 - rx0;
    const int ly = (int)fy0 - ry0;
    const int base = ly * LSTR + lx;
    const float w00 = wy0 * wx0, w01 = wy0 * wx1;
    const float w10 = wy1 * wx0, w11 = wy1 * wx1;
    r0[k] = w00 * lds[0][base]        + w01 * lds[0][base + 1] +
            w10 * lds[0][base + LSTR] + w11 * lds[0][base + LSTR + 1];
    r1[k] = w00 * lds[1][base]        + w01 * lds[1][base + 1] +
            w10 * lds[1][base + LSTR] + w11 * lds[1][base + LSTR + 1];
    r2[k] = w00 * lds[2][base]        + w01 * lds[2][base + 1] +
            w10 * lds[2][base + LSTR] + w11 * lds[2][base + LSTR + 1];
  }

  float* __restrict__ o = out + (size_t)ns * (C_ * HW_) + (size_t)h * W_ + w_base;
  *reinterpret_cast<float4*>(o)            = make_float4(r0[0], r0[1], r0[2], r0[3]);
  *reinterpret_cast<float4*>(o + HW_)      = make_float4(r1[0], r1[1], r1[2], r1[3]);
  *reinterpret_cast<float4*>(o + 2 * HW_)  = make_float4(r2[0], r2[1], r2[2], r2[3]);
}

extern "C" void kernel_launch(void* const* d_in, const int* in_sizes, int n_in,
                              void* d_out, int out_size, void* d_ws,
                              size_t ws_size, hipStream_t stream) {
  const float* x      = (const float*)d_in[0];
  const float* thetas = (const float*)d_in[1];
  float* out          = (float*)d_out;

  dim3 grid(TPL * TPL, N_ * S1_);   // 49 tiles x 544 planes
  rot_bilinear_lds_kernel<<<grid, THREADS, 0, stream>>>(x, thetas, out);
}